// Round 6
// baseline (686.496 us; speedup 1.0000x reference)
//
#include <hip/hip_runtime.h>

#define EPS 1e-5f
#define KK 27

typedef __bf16 bf16x8 __attribute__((ext_vector_type(8)));
typedef float f32x4 __attribute__((ext_vector_type(4)));

__device__ __forceinline__ unsigned short f2bf(float f) {
    union { float f; unsigned u; } v; v.f = f;
    unsigned r = v.u + 0x7fffu + ((v.u >> 16) & 1u);  // round-to-nearest-even
    return (unsigned short)(r >> 16);
}
__device__ __forceinline__ float bf2f(unsigned short h) {
    union { unsigned u; float f; } v; v.u = ((unsigned)h) << 16; return v.f;
}

__device__ __forceinline__ f32x4 mfma16(bf16x8 a, bf16x8 b, f32x4 c) {
    return __builtin_amdgcn_mfma_f32_16x16x32_bf16(a, b, c, 0, 0, 0);
}

// s_waitcnt with vmcnt=N, lgkmcnt/expcnt untouched (gfx9 encoding:
// vmcnt[3:0]@0, exp@4, lgkm@8, vmcnt[5:4]@14). N in {0,4,8,12}.
__device__ __forceinline__ void wait_vm(int n) {
    if (n >= 12)     __builtin_amdgcn_s_waitcnt(0xF7C);
    else if (n >= 8) __builtin_amdgcn_s_waitcnt(0xF78);
    else if (n >= 4) __builtin_amdgcn_s_waitcnt(0xF74);
    else             __builtin_amdgcn_s_waitcnt(0xF70);
}

// async gather of 32 rows (128B each) into a 4KB LDS slot; per-lane source
// address, wave-uniform dest + lane*16. Chunk-XOR swizzle (chunk ^= row&7)
// keeps the later ds_read_b128 at the structural bank minimum.
__device__ __forceinline__ void stage_rows(const unsigned short* __restrict__ xin,
                                           const int* idxv, int csel,
                                           unsigned short* ldsslot) {
    #pragma unroll
    for (int s = 0; s < 4; ++s) {
        const unsigned short* src = xin + (long)idxv[s] * 64 + csel * 8;
        __builtin_amdgcn_global_load_lds(
            (const __attribute__((address_space(1))) unsigned*)src,
            (__attribute__((address_space(3))) unsigned*)(ldsslot + s * 512),
            16, 0, 0);
    }
}

// ---------------- map inversion ----------------
__global__ void fill_i32(int* __restrict__ p, long tot, int val) {
    long i = (long)blockIdx.x * blockDim.x + threadIdx.x;
    if (i < tot) p[i] = val;
}

__global__ void invert_map(const int* __restrict__ km_in, const int* __restrict__ km_out,
                           int* __restrict__ dense, int M, int nrows) {
    long i = (long)blockIdx.x * blockDim.x + threadIdx.x;
    if (i >= (long)KK * M) return;
    int k = (int)(i / M);
    int ki = km_in[i];
    if (ki < nrows) dense[(long)k * (nrows + 1) + km_out[i]] = ki;
}

// ---------------- weight prep ----------------
__global__ void wt_bf16(const float* __restrict__ W, unsigned short* __restrict__ Wt,
                        int Cin, int Cout) {
    long i = (long)blockIdx.x * blockDim.x + threadIdx.x;
    long tot = (long)KK * Cin * Cout;
    if (i >= tot) return;
    int k  = (int)(i / (Cin * Cout));
    int r  = (int)(i % (Cin * Cout));
    int ci = r / Cout, co = r % Cout;
    Wt[((long)k * Cout + co) * Cin + ci] = f2bf(W[i]);
}

__global__ void w1t_bf16(const float* __restrict__ W1, unsigned short* __restrict__ W1t) {
    int i = blockIdx.x * blockDim.x + threadIdx.x;
    if (i >= 64 * 32) return;
    int c = i / 32, kk = i % 32;
    W1t[i] = (kk < KK) ? f2bf(W1[kk * 64 + c]) : (unsigned short)0;
}

// ---------------- conv1 gather-MFMA (1->64), fused stats ----------------
__global__ __launch_bounds__(256, 2) void conv1_mfma(const float* __restrict__ feats,
                                                     const unsigned short* __restrict__ W1t,
                                                     const int* __restrict__ dense, int n,
                                                     unsigned short* __restrict__ out,
                                                     float* __restrict__ st) {
    int wave = threadIdx.x >> 6, lane = threadIdx.x & 63;
    int m16 = lane & 15, quad = lane >> 4;
    long tile = (long)blockIdx.x * 4 + wave;
    long j0 = tile * 32;
    if (j0 >= n) return;
    int jm[2] = {(int)j0 + m16, (int)j0 + 16 + m16};
    if (jm[0] > n) jm[0] = n;
    if (jm[1] > n) jm[1] = n;

    int idx[2][8];
    #pragma unroll
    for (int i = 0; i < 8; ++i) {
        int kk = quad * 8 + i;
        bool kv = (kk < KK);
        #pragma unroll
        for (int t2 = 0; t2 < 2; ++t2)
            idx[t2][i] = kv ? dense[(long)kk * (n + 1) + jm[t2]] : n;
    }
    float f[2][8];
    #pragma unroll
    for (int i = 0; i < 8; ++i)
        #pragma unroll
        for (int t2 = 0; t2 < 2; ++t2) {
            int r = idx[t2][i];
            f[t2][i] = (r < n) ? feats[r] : 0.f;
        }

    union { bf16x8 v; unsigned short s[8]; } a[2];
    #pragma unroll
    for (int t2 = 0; t2 < 2; ++t2)
        #pragma unroll
        for (int i = 0; i < 8; ++i) a[t2].s[i] = f2bf(f[t2][i]);

    f32x4 acc[2][4];
    #pragma unroll
    for (int t2 = 0; t2 < 2; ++t2)
        #pragma unroll
        for (int t = 0; t < 4; ++t) acc[t2][t] = (f32x4){0.f, 0.f, 0.f, 0.f};

    const unsigned short* wb = W1t + quad * 8;
    #pragma unroll
    for (int t = 0; t < 4; ++t) {
        bf16x8 b = *(const bf16x8*)(wb + (t * 16 + m16) * 32);
        acc[0][t] = mfma16(a[0].v, b, acc[0][t]);
        acc[1][t] = mfma16(a[1].v, b, acc[1][t]);
    }

    #pragma unroll
    for (int t2 = 0; t2 < 2; ++t2) {
        long row = j0 + t2 * 16 + quad * 4;
        #pragma unroll
        for (int t = 0; t < 4; ++t)
            #pragma unroll
            for (int r2 = 0; r2 < 4; ++r2) {
                long rr = row + r2;
                if (rr < n) out[rr * 64 + t * 16 + m16] = f2bf(acc[t2][t][r2]);
            }
    }
    // fused stats (sentinel rows contribute 0)
    #pragma unroll
    for (int t = 0; t < 4; ++t) {
        float s = 0.f, q = 0.f;
        #pragma unroll
        for (int t2 = 0; t2 < 2; ++t2)
            #pragma unroll
            for (int r2 = 0; r2 < 4; ++r2) { float v = acc[t2][t][r2]; s += v; q += v * v; }
        s += __shfl_xor(s, 16); q += __shfl_xor(q, 16);
        s += __shfl_xor(s, 32); q += __shfl_xor(q, 32);
        if (quad == 0) {
            atomicAdd(&st[t * 16 + m16], s);
            atomicAdd(&st[64 + t * 16 + m16], q);
        }
    }
}

// ---------------- BN+ReLU in place on bf16, vectorized 8-wide ----------------
__global__ void bnrelu1_vec(unsigned short* __restrict__ x, const float* __restrict__ stats,
                            const float* __restrict__ g, const float* __restrict__ be, long n) {
    __shared__ float sc[64], sh[64];
    int tid = threadIdx.x;
    if (tid < 64) {
        float mu  = stats[tid] / (float)n;
        float var = stats[64 + tid] / (float)n - mu * mu;
        float s   = g[tid] * rsqrtf(var + EPS);
        sc[tid] = s; sh[tid] = be[tid] - mu * s;
    }
    __syncthreads();
    long i = (long)blockIdx.x * 256 + tid;   // 8-half chunks
    long tot = (n + 1) * 8;
    if (i >= tot) return;
    long j = i >> 3; int c0 = (int)(i & 7) * 8;
    union { bf16x8 v; unsigned short s[8]; } u, o;
    if (j < n) {
        u.v = *(const bf16x8*)(x + j * 64 + c0);
        #pragma unroll
        for (int t = 0; t < 8; ++t) {
            float f = bf2f(u.s[t]) * sc[c0 + t] + sh[c0 + t];
            o.s[t] = f2bf(f > 0.f ? f : 0.f);
        }
    } else {
        #pragma unroll
        for (int t = 0; t < 8; ++t) o.s[t] = 0;
    }
    *(bf16x8*)(x + j * 64 + c0) = o.v;
}

// ---------------- MFMA gather-conv: LDS-staged async pipeline, fused stats ----------------
// One wave = 32 rows x NT*16 cols. A-rows go global->LDS via global_load_lds
// (unsinkable) in a DEPTH=4 ring; wait_vm counts only our own stage insts
// (12 newer stages when consuming a slot -> always safe).
template <int NT, int MINW, bool BF16OUT>
__global__ __launch_bounds__(256, MINW) void conv_mfma(const unsigned short* __restrict__ xin,
                                                       const unsigned short* __restrict__ Wt,
                                                       const int* __restrict__ dense,
                                                       void* __restrict__ outv, int n,
                                                       float* __restrict__ st) {
    constexpr int COUT = NT * 16;
    __shared__ __align__(16) unsigned short lds[4][4][2048];   // [wave][slot][4KB]
    int wave = threadIdx.x >> 6;
    int lane = threadIdx.x & 63;
    int m16 = lane & 15, quad = lane >> 4;

    long tile = (long)blockIdx.x * 4 + wave;
    long j0 = tile * 32;
    if (j0 >= n) return;

    int csel = (lane & 7) ^ ((lane >> 3) & 7);
    int jrow[4];
    #pragma unroll
    for (int s = 0; s < 4; ++s) {
        int jr = (int)j0 + s * 8 + (lane >> 3);
        jrow[s] = (jr > n) ? n : jr;          // dense[k][n]==n -> zero row
    }

    // ds_read offsets (halves) within a slot: row r=t2*16+m16, chunk q=4s+quad,
    // stored at physical chunk q ^ (r&7)
    int aoff[2][2];
    #pragma unroll
    for (int t2 = 0; t2 < 2; ++t2)
        #pragma unroll
        for (int s = 0; s < 2; ++s) {
            int r = t2 * 16 + m16;
            aoff[t2][s] = r * 64 + (((4 * s + quad) ^ (r & 7)) * 8);
        }

    // prologue: idx for slots 0..4, stage slots 0..2
    int tmp[3][4];
    #pragma unroll
    for (int k = 0; k < 3; ++k)
        #pragma unroll
        for (int s = 0; s < 4; ++s) tmp[k][s] = dense[(long)k * (n + 1) + jrow[s]];
    int idxq[4][4];
    #pragma unroll
    for (int s = 0; s < 4; ++s) {
        idxq[3][s] = dense[(long)3 * (n + 1) + jrow[s]];
        idxq[0][s] = dense[(long)4 * (n + 1) + jrow[s]];
    }
    #pragma unroll
    for (int k = 0; k < 3; ++k) stage_rows(xin, tmp[k], csel, &lds[wave][k][0]);

    const unsigned short* wbase = Wt + quad * 8;
    bf16x8 bcur[NT][2];
    #pragma unroll
    for (int t = 0; t < NT; ++t)
        #pragma unroll
        for (int s = 0; s < 2; ++s)
            bcur[t][s] = *(const bf16x8*)(wbase + (t * 16 + m16) * 64 + s * 32);

    f32x4 acc[2][NT];
    #pragma unroll
    for (int t2 = 0; t2 < 2; ++t2)
        #pragma unroll
        for (int t = 0; t < NT; ++t) acc[t2][t] = (f32x4){0.f, 0.f, 0.f, 0.f};

    #pragma unroll
    for (int k = 0; k < KK; ++k) {
        // pipelined index loads (for slot k+5, staged at iter k+2)
        if (k + 5 < KK) {
            const int* dk = dense + (long)(k + 5) * (n + 1);
            #pragma unroll
            for (int s = 0; s < 4; ++s) idxq[(k + 5) & 3][s] = dk[jrow[s]];
        }
        // stage slot k+3
        if (k + 3 < KK)
            stage_rows(xin, idxq[(k + 3) & 3], csel, &lds[wave][(k + 3) & 3][0]);
        // wait for slot k (only counts our unsinkable stage insts -> safe)
        int nx = KK - 1 - k; nx = nx > 3 ? 3 : nx;
        wait_vm(4 * nx);
        // consume slot k
        bf16x8 a[2][2];
        #pragma unroll
        for (int t2 = 0; t2 < 2; ++t2)
            #pragma unroll
            for (int s = 0; s < 2; ++s)
                a[t2][s] = *(const bf16x8*)&lds[wave][k & 3][aoff[t2][s]];
        #pragma unroll
        for (int s = 0; s < 2; ++s)
            #pragma unroll
            for (int t = 0; t < NT; ++t) {
                acc[0][t] = mfma16(a[0][s], bcur[t][s], acc[0][t]);
                acc[1][t] = mfma16(a[1][s], bcur[t][s], acc[1][t]);
            }
        // B for next iteration (plain loads; L2-hot, one batched latency)
        if (k + 1 < KK) {
            const unsigned short* wk = wbase + (long)(k + 1) * (COUT * 64);
            #pragma unroll
            for (int t = 0; t < NT; ++t)
                #pragma unroll
                for (int s = 0; s < 2; ++s)
                    bcur[t][s] = *(const bf16x8*)(wk + (t * 16 + m16) * 64 + s * 32);
        }
    }

    #pragma unroll
    for (int t2 = 0; t2 < 2; ++t2) {
        long row = j0 + t2 * 16 + quad * 4;    // D: col=m16, row=quad*4+reg
        #pragma unroll
        for (int t = 0; t < NT; ++t)
            #pragma unroll
            for (int r2 = 0; r2 < 4; ++r2) {
                long rr = row + r2;
                if (rr < n) {
                    long o = rr * COUT + t * 16 + m16;
                    if (BF16OUT) ((unsigned short*)outv)[o] = f2bf(acc[t2][t][r2]);
                    else         ((float*)outv)[o] = acc[t2][t][r2];
                }
            }
    }
    // fused per-channel stats
    #pragma unroll
    for (int t = 0; t < NT; ++t) {
        float s = 0.f, q = 0.f;
        #pragma unroll
        for (int t2 = 0; t2 < 2; ++t2)
            #pragma unroll
            for (int r2 = 0; r2 < 4; ++r2) { float v = acc[t2][t][r2]; s += v; q += v * v; }
        s += __shfl_xor(s, 16); q += __shfl_xor(q, 16);
        s += __shfl_xor(s, 32); q += __shfl_xor(q, 32);
        if (quad == 0) {
            atomicAdd(&st[t * 16 + m16], s);
            atomicAdd(&st[COUT + t * 16 + m16], q);
        }
    }
}

// ---------------- BN+ReLU on bf16 x2 fused with segment-max pool ----------------
__global__ void pool_kernel(const unsigned short* __restrict__ x, const float* __restrict__ stats,
                            const float* __restrict__ g, const float* __restrict__ be,
                            const int* __restrict__ seg, long n, unsigned* __restrict__ pooled) {
    long j = (long)blockIdx.x * 4 + threadIdx.y;
    if (j >= n) return;
    int c = threadIdx.x;
    float mu  = stats[c] / (float)n;
    float var = stats[64 + c] / (float)n - mu * mu;
    float rs  = rsqrtf(var + EPS);
    float v   = g[c] * (bf2f(x[j * 64 + c]) - mu) * rs + be[c];
    if (v < 0.f) v = 0.f;
    atomicMax(&pooled[(long)seg[j] * 64 + c], __float_as_uint(v));
}

__global__ void pooled_bf16_vec(const unsigned* __restrict__ pooled, long np,
                                unsigned short* __restrict__ out) {
    long i = (long)blockIdx.x * 256 + threadIdx.x;   // 8-half chunks
    long tot = (np + 1) * 8;
    if (i >= tot) return;
    long j = i >> 3; int c0 = (int)(i & 7) * 8;
    union { bf16x8 v; unsigned short s[8]; } o;
    if (j < np) {
        #pragma unroll
        for (int t = 0; t < 8; ++t)
            o.s[t] = f2bf(__uint_as_float(pooled[j * 64 + c0 + t]));
    } else {
        #pragma unroll
        for (int t = 0; t < 8; ++t) o.s[t] = 0;
    }
    *(bf16x8*)(out + j * 64 + c0) = o.v;
}

// ---------------- final BN+ReLU in place on d_out, float4 ----------------
__global__ void bnrelu_out_vec(float* __restrict__ x, const float* __restrict__ stats,
                               const float* __restrict__ g, const float* __restrict__ be,
                               long n) {
    __shared__ float sc[128], sh[128];
    int tid = threadIdx.x;
    if (tid < 128) {
        float mu  = stats[tid] / (float)n;
        float var = stats[128 + tid] / (float)n - mu * mu;
        float s   = g[tid] * rsqrtf(var + EPS);
        sc[tid] = s; sh[tid] = be[tid] - mu * s;
    }
    __syncthreads();
    long i = (long)blockIdx.x * 256 + tid;   // float4 chunks
    long tot = n * 32;
    if (i >= tot) return;
    int c0 = (int)(i & 31) * 4;
    float4 v = ((float4*)x)[i];
    v.x = v.x * sc[c0]     + sh[c0];     v.x = v.x > 0.f ? v.x : 0.f;
    v.y = v.y * sc[c0 + 1] + sh[c0 + 1]; v.y = v.y > 0.f ? v.y : 0.f;
    v.z = v.z * sc[c0 + 2] + sh[c0 + 2]; v.z = v.z > 0.f ? v.z : 0.f;
    v.w = v.w * sc[c0 + 3] + sh[c0 + 3]; v.w = v.w > 0.f ? v.w : 0.f;
    ((float4*)x)[i] = v;
}

extern "C" void kernel_launch(void* const* d_in, const int* in_sizes, int n_in,
                              void* d_out, int out_size, void* d_ws, size_t ws_size,
                              hipStream_t stream) {
    const float* feats = (const float*)d_in[0];
    const float* W1  = (const float*)d_in[1];
    const float* g1  = (const float*)d_in[3];
    const float* be1 = (const float*)d_in[4];
    const float* W2  = (const float*)d_in[5];
    const float* g2  = (const float*)d_in[7];
    const float* be2 = (const float*)d_in[8];
    const float* W3  = (const float*)d_in[9];
    const float* g3  = (const float*)d_in[11];
    const float* be3 = (const float*)d_in[12];
    const int* km_in   = (const int*)d_in[13];
    const int* km_out  = (const int*)d_in[14];
    const int* pool_seg = (const int*)d_in[15];
    const int* km2_in  = (const int*)d_in[16];
    const int* km2_out = (const int*)d_in[17];

    const int n  = in_sizes[0];           // 160000
    const int M  = in_sizes[13] / KK;
    const int np = out_size / 128;        // N_POOL
    const int M2 = in_sizes[16] / KK;

    // bias terms (b1/b2/b3) skipped: constant per-channel shift cancels through
    // training-mode BatchNorm exactly (mean-subtracted, variance unchanged).

    char* ws = (char*)d_ws;
    size_t off = 0;
    auto alloc = [&](size_t bytes) -> char* {
        char* p = ws + off;
        off += (bytes + 255) & ~(size_t)255;
        return p;
    };
    int* dense1 = (int*)alloc((size_t)KK * (n + 1) * 4);
    int* dense2 = (int*)alloc((size_t)KK * (np + 1) * 4);
    unsigned short* W1t = (unsigned short*)alloc(64 * 32 * 2);
    unsigned short* W2t = (unsigned short*)alloc((size_t)KK * 64 * 64 * 2);
    unsigned short* W3t = (unsigned short*)alloc((size_t)KK * 128 * 64 * 2);
    float* stats = (float*)alloc(4096);
    unsigned short* x1n = (unsigned short*)alloc((size_t)(n + 1) * 64 * 2);
    unsigned short* x2r = (unsigned short*)alloc((size_t)n * 64 * 2);
    unsigned* pooled = (unsigned*)alloc((size_t)np * 64 * 4);
    unsigned short* xpn = (unsigned short*)alloc((size_t)(np + 1) * 64 * 2);
    float* x3 = (float*)d_out;
    if (off > ws_size) return;

    float* stats1 = stats;
    float* stats2 = stats + 128;
    float* stats3 = stats + 256;

    hipMemsetAsync(stats, 0, 4096, stream);
    hipMemsetAsync(pooled, 0, (size_t)np * 64 * 4, stream);

    {
        long t1 = (long)KK * (n + 1);
        fill_i32<<<(int)((t1 + 255) / 256), 256, 0, stream>>>(dense1, t1, n);
        long t2 = (long)KK * (np + 1);
        fill_i32<<<(int)((t2 + 255) / 256), 256, 0, stream>>>(dense2, t2, np);
        long e1 = (long)KK * M;
        invert_map<<<(int)((e1 + 255) / 256), 256, 0, stream>>>(km_in, km_out, dense1, M, n);
        long e2 = (long)KK * M2;
        invert_map<<<(int)((e2 + 255) / 256), 256, 0, stream>>>(km2_in, km2_out, dense2, M2, np);
    }
    {
        w1t_bf16<<<8, 256, 0, stream>>>(W1, W1t);
        long t2 = (long)KK * 64 * 64;
        wt_bf16<<<(int)((t2 + 255) / 256), 256, 0, stream>>>(W2, W2t, 64, 64);
        long t3 = (long)KK * 64 * 128;
        wt_bf16<<<(int)((t3 + 255) / 256), 256, 0, stream>>>(W3, W3t, 64, 128);
    }

    // layer 1 (+stats1 fused)
    {
        long waves = (n + 31) / 32;
        conv1_mfma<<<(int)((waves + 3) / 4), 256, 0, stream>>>(feats, W1t, dense1, n, x1n, stats1);
    }
    {
        long tot = ((long)(n + 1) * 8 + 255) / 256;
        bnrelu1_vec<<<(int)tot, 256, 0, stream>>>(x1n, stats1, g1, be1, n);
    }
    // layer 2 (+stats2 fused)
    {
        long waves = (n + 31) / 32;
        conv_mfma<4, 2, true><<<(int)((waves + 3) / 4), 256, 0, stream>>>(x1n, W2t, dense1, x2r, n, stats2);
    }
    pool_kernel<<<(n + 3) / 4, dim3(64, 4), 0, stream>>>(x2r, stats2, g2, be2, pool_seg, n, pooled);
    {
        long tot = ((long)(np + 1) * 8 + 255) / 256;
        pooled_bf16_vec<<<(int)tot, 256, 0, stream>>>(pooled, np, xpn);
    }
    // layer 3 (+stats3 fused)
    {
        long waves = (np + 31) / 32;
        conv_mfma<8, 2, false><<<(int)((waves + 3) / 4), 256, 0, stream>>>(xpn, W3t, dense2, x3, np, stats3);
    }
    {
        long tot = ((long)np * 32 + 255) / 256;
        bnrelu_out_vec<<<(int)tot, 256, 0, stream>>>(x3, stats3, g3, be3, np);
    }
}